// Round 12
// baseline (659.719 us; speedup 1.0000x reference)
//
#include <hip/hip_runtime.h>
#include <hip/hip_bf16.h>
#include <cstdint>
#include <cstddef>

typedef unsigned short ushort_t;
typedef __bf16 bf16x8 __attribute__((ext_vector_type(8)));
typedef float floatx4 __attribute__((ext_vector_type(4)));

#define S_LEN 2048
#define DIN   512
#define DH    512
#define NHEAD 8
#define NBAT  4
#define NBH   32
#define HP    4096   // NHEAD*DH

// ---------- static device workspace ----------
#define MiB (1024ull * 1024ull)
#define WQT_OFF   (0ull)           //  4 MiB  WqT [8][512e][512d] bf16
#define WKT_OFF   (4ull  * MiB)    //  4 MiB
#define WVT_OFF   (8ull  * MiB)    //  4 MiB
#define WPT_OFF   (12ull * MiB)    //  4 MiB  WpT [512][4096] bf16
#define XBF_OFF   (16ull * MiB)    //  8 MiB  x bf16 [4][2048][512]
#define Q_OFF     (24ull * MiB)    // 64 MiB  [32][2048][512] bf16
#define K_OFF     (88ull * MiB)    // 64 MiB
#define VT_OFF    (152ull * MiB)   // 64 MiB  [32][512][2048] bf16
#define O_OFF     (216ull * MiB)   // 64 MiB  [4][2048][4096] bf16 (cat)
#define LSUM_OFF  (280ull * MiB)   // 256 KiB fp32 [32][2048] (global head idx)
#define P_OFF     (281ull * MiB)   // 128 MiB [16][2048][2048] bf16 (compact cols)
#define PART_OFF  (409ull * MiB)   // 64 MiB  fp32 [4][8192][512] proj partials
#define IDX_OFF   (473ull * MiB)   // 32 KiB  int32 [4][2048] compact->orig key
#define CNT_OFF   (IDX_OFF + 64ull * 1024ull)  // int32 [4][2] {cnt, cnt_pad}
#define KC_OFF    (474ull * MiB)   // 64 MiB  bf16 [32][2048][512] compacted K
#define VTC_OFF   (538ull * MiB)   // 64 MiB  bf16 [32][512][2048] compacted V^T
#define WS_BYTES  (602ull * MiB)

__device__ __align__(256) unsigned char g_ws[WS_BYTES];

// ---------- helpers ----------
__device__ __forceinline__ ushort_t f2bf(float f) {
  union { float f; uint32_t u; } v; v.f = f;
  uint32_t r = v.u + 0x7fffu + ((v.u >> 16) & 1u);
  return (ushort_t)(r >> 16);
}

typedef __attribute__((address_space(3))) uint32_t lds_uint;
typedef __attribute__((address_space(1))) const uint32_t glb_uint;

__device__ __forceinline__ void async16(void* lds, const void* g) {
  __builtin_amdgcn_global_load_lds((glb_uint*)g, (lds_uint*)lds, 16, 0, 0);
}

// scheduling fence + hw barrier (only used OUTSIDE the 8-phase main loop)
#define BBAR() do { \
    __builtin_amdgcn_sched_barrier(0); \
    __builtin_amdgcn_s_barrier(); \
    __builtin_amdgcn_sched_barrier(0); \
  } while (0)

// raw barrier for the 8-phase loop — NO sched fences
#define RBAR() __builtin_amdgcn_s_barrier()

// ============================================================================
// 256x256 GEMM core — r6 8-phase structure (best measured config). BK=64,
// 512 thr = 8 waves, 2 K-tiles per iteration. vmcnt(4) only at ph3/ph7
// closings; vmcnt(0) only in the last iteration. LDS swizzle conflict-free
// (r1). Requires kdim % 128 == 0 (cnt_pad is a multiple of 256).
// ============================================================================

#define STG_A(dbuf, hh, kt) do { \
    const ushort_t* _g = gA + (size_t)(kt) * 64 + (size_t)(hh) * a128; \
    char* _s = sAh + (dbuf) * 32768 + (hh) * 16384; \
    async16(_s, _g); \
    async16(_s + 8192, _g + a64); \
  } while (0)

#define STG_B(dbuf, hh, kt) do { \
    const ushort_t* _g = gB + (size_t)(kt) * 64 + (size_t)(hh) * b128; \
    char* _s = sBh + (dbuf) * 32768 + (hh) * 16384; \
    async16(_s, _g); \
    async16(_s + 8192, _g + b64); \
  } while (0)

#define LD_A2(dst, buf, qm) do { \
    const char* _b = (const char*)As + (buf) * 32768 + (qm) * 16384 + aoff0; \
    _Pragma("unroll") \
    for (int _i = 0; _i < 4; ++_i) { \
      dst[_i][0] = *(const bf16x8*)(_b + (_i << 11) + swz0); \
      dst[_i][1] = *(const bf16x8*)(_b + (_i << 11) + swz1); \
    } } while (0)

#define LD_B2(dst, buf, qn) do { \
    const char* _b = (const char*)Bs + (buf) * 32768 + (qn) * 16384 + boff0; \
    _Pragma("unroll") \
    for (int _j = 0; _j < 2; ++_j) { \
      dst[_j][0] = *(const bf16x8*)(_b + (_j << 11) + swz0); \
      dst[_j][1] = *(const bf16x8*)(_b + (_j << 11) + swz1); \
    } } while (0)

#define MM(q, AF, BF) do { \
    _Pragma("unroll") \
    for (int _i = 0; _i < 4; ++_i) { \
      _Pragma("unroll") \
      for (int _j = 0; _j < 2; ++_j) { \
        acc[q][_i][_j] = __builtin_amdgcn_mfma_f32_16x16x32_bf16(AF[_i][0], BF[_j][0], acc[q][_i][_j], 0, 0, 0); \
        acc[q][_i][_j] = __builtin_amdgcn_mfma_f32_16x16x32_bf16(AF[_i][1], BF[_j][1], acc[q][_i][_j], 0, 0, 0); \
      } \
    } \
  } while (0)

#define PHASE(q, AF, BF, STMT) do { \
    STMT; \
    RBAR(); \
    __builtin_amdgcn_s_setprio(1); \
    MM(q, AF, BF); \
    __builtin_amdgcn_s_setprio(0); \
    RBAR(); \
  } while (0)

__device__ __forceinline__ void gemm256_core(
    const ushort_t* __restrict__ A, const ushort_t* __restrict__ Bt,
    int lda, int ldb, int kdim,
    ushort_t* As, ushort_t* Bs, floatx4 acc[4][4][2])
{
  const int t = threadIdx.x;
  const int w = t >> 6, l = t & 63;
  const int l15 = l & 15, lq = l >> 4;
  const int wq_r = w >> 2, wq_c = w & 3;

  const int r0 = t >> 3, c0 = t & 7;
  const ushort_t* gA = A + (size_t)r0 * lda + ((c0 ^ (r0 & 7)) << 3);
  const ushort_t* gB = Bt + (size_t)r0 * ldb + ((c0 ^ (r0 & 7)) << 3);
  const size_t a64 = (size_t)64 * lda, b64 = (size_t)64 * ldb;
  const size_t a128 = (size_t)128 * lda, b128 = (size_t)128 * ldb;
  char* sAh = (char*)As + (w << 10);
  char* sBh = (char*)Bs + (w << 10);

  const int aoff0 = ((wq_r << 6) + l15) << 7;
  const int boff0 = ((wq_c << 5) + l15) << 7;
  const int l7 = l15 & 7;
  const int swz0 = (lq ^ l7) << 4;
  const int swz1 = ((4 + lq) ^ l7) << 4;

  const int nt = kdim >> 6;   // multiple of 4 for all our shapes

#pragma unroll
  for (int q = 0; q < 4; ++q)
#pragma unroll
    for (int i = 0; i < 4; ++i)
#pragma unroll
      for (int j = 0; j < 2; ++j)
        acc[q][i][j] = (floatx4){0.f, 0.f, 0.f, 0.f};

  // prologue: tile0 all 4 halves + A0/B0 of tile1; keep newest 2 in flight
  STG_A(0, 0, 0);
  STG_B(0, 0, 0);
  STG_B(0, 1, 0);
  STG_A(0, 1, 0);
  STG_A(1, 0, 1);
  STG_B(1, 0, 1);
  asm volatile("s_waitcnt vmcnt(4)" ::: "memory");
  RBAR();

  bf16x8 a[4][2], b0[2][2], b1[2][2];

#pragma unroll 1
  for (int T = 0; T < nt; T += 2) {
    const bool more = (T + 2 < nt);
    LD_A2(a, 0, 0);
    LD_B2(b0, 0, 0);
    PHASE(0, a, b0, STG_B(1, 1, T + 1));
    LD_B2(b1, 0, 1);
    PHASE(1, a, b1, STG_A(1, 1, T + 1));
    LD_A2(a, 0, 1);
    PHASE(2, a, b1, if (more) STG_A(0, 0, T + 2));
    {
      if (more) STG_B(0, 0, T + 2);
      RBAR();
      __builtin_amdgcn_s_setprio(1);
      MM(3, a, b0);
      __builtin_amdgcn_s_setprio(0);
      if (more) asm volatile("s_waitcnt vmcnt(4)" ::: "memory");
      else      asm volatile("s_waitcnt vmcnt(0)" ::: "memory");
      RBAR();
    }
    LD_A2(a, 1, 0);
    LD_B2(b0, 1, 0);
    PHASE(0, a, b0, if (more) STG_B(0, 1, T + 2));
    LD_B2(b1, 1, 1);
    PHASE(1, a, b1, if (more) STG_A(0, 1, T + 2));
    LD_A2(a, 1, 1);
    PHASE(2, a, b1, if (more) STG_A(1, 0, T + 3));
    {
      if (more) STG_B(1, 0, T + 3);
      RBAR();
      __builtin_amdgcn_s_setprio(1);
      MM(3, a, b0);
      __builtin_amdgcn_s_setprio(0);
      if (more) asm volatile("s_waitcnt vmcnt(4)" ::: "memory");
      else      asm volatile("s_waitcnt vmcnt(0)" ::: "memory");
      RBAR();
    }
  }
}

// ---------- fp32 -> bf16 bulk convert into g_ws ----------
__global__ __launch_bounds__(256) void convert_f32_bf16(
    const float* __restrict__ src, size_t dstOff, int n)
{
  ushort_t* dst = (ushort_t*)(g_ws + dstOff);
  int i = (blockIdx.x * 256 + threadIdx.x) * 4;
  if (i >= n) return;
  float4 v = *(const float4*)(src + i);
  ushort_t o[4] = {f2bf(v.x), f2bf(v.y), f2bf(v.z), f2bf(v.w)};
  *(uint2*)(dst + i) = *(const uint2*)o;
}

// ---------- fp32 [R][C] -> bf16 [C][R] transpose into g_ws ----------
__global__ __launch_bounds__(256) void transpose_f32_bf16(
    const float* __restrict__ src, size_t dstOff, int R, int C)
{
  __shared__ ushort_t tile[32][33];
  ushort_t* dst = (ushort_t*)(g_ws + dstOff) + (size_t)blockIdx.z * R * C;
  src += (size_t)blockIdx.z * R * C;
  int r0 = blockIdx.y * 32, c0 = blockIdx.x * 32;
  int tx = threadIdx.x & 31, ty = threadIdx.x >> 5;
  for (int i = ty; i < 32; i += 8)
    tile[i][tx] = f2bf(src[(size_t)(r0 + i) * C + (c0 + tx)]);
  __syncthreads();
  for (int i = ty; i < 32; i += 8)
    dst[(size_t)(c0 + i) * R + (r0 + tx)] = tile[tx][i];
}

// ---------- merged Wq/Wk/Wv transpose: z in [0,24) ----------
__global__ __launch_bounds__(256) void transpose_w3(
    const float* __restrict__ Wq, const float* __restrict__ Wk,
    const float* __restrict__ Wv)
{
  __shared__ ushort_t tile[32][33];
  const int z = blockIdx.z;
  const int sel = z >> 3, h = z & 7;
  const float* src = ((sel == 0) ? Wq : (sel == 1) ? Wk : Wv)
                     + (size_t)h * DIN * DH;
  ushort_t* dst = (ushort_t*)(g_ws + ((sel == 0) ? WQT_OFF
                                      : (sel == 1) ? WKT_OFF : WVT_OFF))
                  + (size_t)h * DIN * DH;
  int r0 = blockIdx.y * 32, c0 = blockIdx.x * 32;
  int tx = threadIdx.x & 31, ty = threadIdx.x >> 5;
  for (int i = ty; i < 32; i += 8)
    tile[i][tx] = f2bf(src[(size_t)(r0 + i) * DH + (c0 + tx)]);
  __syncthreads();
  for (int i = ty; i < 32; i += 8)
    dst[(size_t)(c0 + i) * DIN + (r0 + tx)] = tile[tx][i];
}

// ---------- zero lsum (32*2048 fp32 = 256 KiB), once per launch ----------
__global__ __launch_bounds__(256) void zero_lsum()
{
  float* lsum = (float*)(g_ws + LSUM_OFF);
  int i = (blockIdx.x * 256 + threadIdx.x) * 4;
  *(float4*)(lsum + i) = (float4){0.f, 0.f, 0.f, 0.f};
}

// ---------- mask scan: per batch, compact index list + counts ----------
// idx[b][j] = original key position of j-th unmasked key (ascending);
// cnt_pad = cnt rounded up to 256 (core needs kdim % 128 == 0).
__global__ __launch_bounds__(64) void scan_mask(const int* __restrict__ mask)
{
  const int b = blockIdx.x, l = threadIdx.x;
  const int* mb = mask + (size_t)b * S_LEN;
  int* idx = (int*)(g_ws + IDX_OFF) + b * S_LEN;
  const int base = l * 32;
  int c = 0;
#pragma unroll
  for (int i = 0; i < 32; ++i) c += (mb[base + i] != 0);
  int pre = c;
  for (int d = 1; d < 64; d <<= 1) {
    int v = __shfl_up(pre, d);
    if (l >= d) pre += v;
  }
  int p = pre - c;
  for (int i = 0; i < 32; ++i)
    if (mb[base + i] != 0) idx[p++] = base + i;
  if (l == 63) {
    int* cp = (int*)(g_ws + CNT_OFF) + b * 2;
    cp[0] = pre;
    cp[1] = (pre + 255) & ~255;
  }
}

// ---------- gather unmasked K rows -> Kc (zero-fill padded rows) ----------
__global__ __launch_bounds__(256) void compact_k()
{
  const int bh = blockIdx.y, b = bh >> 3;
  const int* cp = (const int*)(g_ws + CNT_OFF) + b * 2;
  const int cnt = cp[0], cnt_pad = cp[1];
  const int w = threadIdx.x >> 6, l = threadIdx.x & 63;
  const int j = blockIdx.x * 4 + w;
  if (j >= cnt_pad) return;
  ushort_t* dst = (ushort_t*)(g_ws + KC_OFF)
                  + ((size_t)bh * S_LEN + j) * DH + l * 8;
  if (j < cnt) {
    const int* idx = (const int*)(g_ws + IDX_OFF) + b * S_LEN;
    const ushort_t* src = (const ushort_t*)(g_ws + K_OFF)
                          + ((size_t)bh * S_LEN + idx[j]) * DH + l * 8;
    *(uint4*)dst = *(const uint4*)src;
  } else {
    *(uint4*)dst = (uint4){0, 0, 0, 0};
  }
}

// ---------- gather unmasked V^T columns -> VTc (zero-fill padding) ----------
__global__ __launch_bounds__(256) void compact_vt()
{
  const int e = blockIdx.x, bh = blockIdx.y, b = bh >> 3;
  const int* cp = (const int*)(g_ws + CNT_OFF) + b * 2;
  const int cnt = cp[0], cnt_pad = cp[1];
  const int j0 = threadIdx.x * 8;
  if (j0 >= cnt_pad) return;
  const int* idx = (const int*)(g_ws + IDX_OFF) + b * S_LEN;
  const ushort_t* src = (const ushort_t*)(g_ws + VT_OFF)
                        + ((size_t)bh * DH + e) * S_LEN;
  ushort_t* dst = (ushort_t*)(g_ws + VTC_OFF)
                  + ((size_t)bh * DH + e) * S_LEN + j0;
  ushort_t v[8];
#pragma unroll
  for (int r = 0; r < 8; ++r) {
    const int j = j0 + r;
    v[r] = (j < cnt) ? src[idx[j]] : (ushort_t)0;
  }
  *(uint4*)dst = *(const uint4*)v;
}

// ---------- QKV projection (256² core): z in [0,96) ----------
__global__ __launch_bounds__(512, 2) void qkv_gemm(
    const float* __restrict__ bq, const float* __restrict__ bk,
    const float* __restrict__ bv)
{
  __shared__ __align__(16) ushort_t SH[65536];   // 128 KiB
  ushort_t* As = SH;
  ushort_t* Bs = SH + 32768;
  const int z = blockIdx.z;
  const int bh = z & 31, sel = z >> 5, b = bh >> 3, h = bh & 7;
  const size_t wOff = (sel == 0) ? WQT_OFF : (sel == 1) ? WKT_OFF : WVT_OFF;
  const float* bias = ((sel == 0) ? bq : (sel == 1) ? bk : bv) + h * DH;
  const int tileM = blockIdx.y * 256, tileN = blockIdx.x * 256;

  const ushort_t* A  = (const ushort_t*)(g_ws + XBF_OFF)
                       + ((size_t)b * S_LEN + tileM) * DIN;
  const ushort_t* Bt = (const ushort_t*)(g_ws + wOff)
                       + ((size_t)h * DH + tileN) * DIN;
  floatx4 acc[4][4][2];
  gemm256_core(A, Bt, DIN, DIN, DIN, As, Bs, acc);

  const int t = threadIdx.x, w = t >> 6, l = t & 63;
  const int l15 = l & 15, lq = l >> 4;
  const int wq_r = w >> 2, wq_c = w & 3;
  const int QM[4] = {0, 0, 1, 1}, QN[4] = {0, 1, 1, 0};

  if (sel == 2) {
    // ---- VT transpose-bounce (r3-proven: fixes 4KB-stride scatter) ----
    char* SB = (char*)SH;
    BBAR();   // core's reads all done; safe to reuse SH
#pragma unroll
    for (int q = 0; q < 4; ++q) {
#pragma unroll
      for (int j = 0; j < 2; ++j) {
        const int nl = QN[q] * 128 + wq_c * 32 + j * 16 + l15;
        const float bsn = bias[tileN + nl];
#pragma unroll
        for (int i = 0; i < 4; ++i) {
          const int ml = QM[q] * 128 + wq_r * 64 + i * 16 + lq * 4;
          ushort_t pk[4];
#pragma unroll
          for (int r = 0; r < 4; ++r) pk[r] = f2bf(acc[q][i][j][r] + bsn);
          const int byte = nl * 512 + (((ml >> 3) ^ (nl & 7)) << 4) + (ml & 7) * 2;
          *(uint2*)(SB + byte) = *(const uint2*)pk;
        }
      }
    }
    BBAR();
    ushort_t* VTb = (ushort_t*)(g_ws + VT_OFF)
                    + ((size_t)bh * DH + tileN) * S_LEN + tileM;
#pragma unroll
    for (int s = 0; s < 16; ++s) {
      const int nl = (w << 5) + (s << 1) + (l >> 5);
      const int c  = l & 31;
      const uint4 v = *(const uint4*)(SB + nl * 512 + ((c ^ (nl & 7)) << 4));
      *(uint4*)(VTb + (size_t)nl * S_LEN + c * 8) = v;
    }
  } else {
    // ---- Q/K direct stores (r9: bouncing these regresses) ----
    ushort_t* Db = (ushort_t*)(g_ws + ((sel == 0) ? Q_OFF : K_OFF));
#pragma unroll
    for (int q = 0; q < 4; ++q) {
#pragma unroll
      for (int j = 0; j < 2; ++j) {
        const int n = tileN + QN[q] * 128 + wq_c * 32 + j * 16 + l15;
        const float bsn = bias[n];
#pragma unroll
        for (int i = 0; i < 4; ++i) {
#pragma unroll
          for (int r = 0; r < 4; ++r) {
            const int m = tileM + QM[q] * 128 + wq_r * 64 + i * 16 + lq * 4 + r;
            Db[((size_t)bh * S_LEN + m) * DH + n] = f2bf(acc[q][i][j][r] + bsn);
          }
        }
      }
    }
  }
}

// ---------- scores on COMPACTED keys + exp + fused row-sum ----------
// B = Kc[bh]; N-axis is the compacted key index. Tiles beyond cnt_pad exit.
// p = exp(min(s,30)) for compact idx < cnt, else 0 (covers zero-padded tail).
__global__ __launch_bounds__(512, 2) void scores_kernel(int c0)
{
  const int hl = blockIdx.z, bh = c0 + hl, b = bh >> 3;
  const int* cp = (const int*)(g_ws + CNT_OFF) + b * 2;
  const int cnt = cp[0], cnt_pad = cp[1];
  const int tileM = blockIdx.y * 256, tileN = blockIdx.x * 256;
  if (tileN >= cnt_pad) return;   // uniform per block; before any barrier

  __shared__ __align__(16) ushort_t SH[65536];
  ushort_t* As = SH;
  ushort_t* Bs = SH + 32768;

  const ushort_t* A  = (const ushort_t*)(g_ws + Q_OFF)
                       + ((size_t)bh * S_LEN + tileM) * DH;
  const ushort_t* Bt = (const ushort_t*)(g_ws + KC_OFF)
                       + ((size_t)bh * S_LEN + tileN) * DH;
  floatx4 acc[4][4][2];
  gemm256_core(A, Bt, DH, DH, DH, As, Bs, acc);

  const float scale = 0.04419417382415922f;  // 1/sqrt(512)
  const int t = threadIdx.x, w = t >> 6, l = t & 63;
  const int l15 = l & 15, lq = l >> 4;
  const int wq_r = w >> 2, wq_c = w & 3;
  const int QM[4] = {0, 0, 1, 1}, QN[4] = {0, 1, 1, 0};
  ushort_t* Pp = (ushort_t*)(g_ws + P_OFF) + (size_t)hl * S_LEN * S_LEN;
  float* lsum = (float*)(g_ws + LSUM_OFF);   // [32][2048], global bh index

  float rsum[2][4][4];
#pragma unroll
  for (int qm = 0; qm < 2; ++qm)
#pragma unroll
    for (int i = 0; i < 4; ++i)
#pragma unroll
      for (int r = 0; r < 4; ++r) rsum[qm][i][r] = 0.f;

#pragma unroll
  for (int q = 0; q < 4; ++q) {
#pragma unroll
    for (int j = 0; j < 2; ++j) {
      const int n = tileN + QN[q] * 128 + wq_c * 32 + j * 16 + l15;
      const int live = (n < cnt);
#pragma unroll
      for (int i = 0; i < 4; ++i) {
#pragma unroll
        for (int r = 0; r < 4; ++r) {
          const int m = tileM + QM[q] * 128 + wq_r * 64 + i * 16 + lq * 4 + r;
          float s = fminf(acc[q][i][j][r] * scale, 30.f);  // clamp: no inf
          const float p = live ? __expf(s) : 0.f;
          rsum[QM[q]][i][r] += p;
          Pp[(size_t)m * S_LEN + n] = f2bf(p);
        }
      }
    }
  }
#pragma unroll
  for (int qm = 0; qm < 2; ++qm) {
#pragma unroll
    for (int i = 0; i < 4; ++i) {
#pragma unroll
      for (int r = 0; r < 4; ++r) {
        float v = rsum[qm][i][r];
        v += __shfl_xor(v, 1);
        v += __shfl_xor(v, 2);
        v += __shfl_xor(v, 4);
        v += __shfl_xor(v, 8);
        if (l15 == 0) {
          const int m = tileM + qm * 128 + wq_r * 64 + i * 16 + lq * 4 + r;
          atomicAdd(&lsum[(size_t)bh * S_LEN + m], v);
        }
      }
    }
  }
}

// ---------- P*V on compacted K-dim, divide by rowsum, cat-layout O ----------
__global__ __launch_bounds__(512, 2) void pv_kernel(int c0)
{
  __shared__ __align__(16) ushort_t SH[65536];
  ushort_t* As = SH;
  ushort_t* Bs = SH + 32768;
  const int hl = blockIdx.z, bh = c0 + hl, b = bh >> 3, h = bh & 7;
  const int* cp = (const int*)(g_ws + CNT_OFF) + b * 2;
  const int cnt_pad = cp[1];
  const int tileM = blockIdx.y * 256, tileN = blockIdx.x * 256;

  const ushort_t* A  = (const ushort_t*)(g_ws + P_OFF)
                       + (size_t)hl * S_LEN * S_LEN + (size_t)tileM * S_LEN;
  const ushort_t* Bt = (const ushort_t*)(g_ws + VTC_OFF)
                       + ((size_t)bh * DH + tileN) * S_LEN;
  floatx4 acc[4][4][2];
  gemm256_core(A, Bt, S_LEN, S_LEN, cnt_pad, As, Bs, acc);

  const float* lsum = (const float*)(g_ws + LSUM_OFF);
  ushort_t* Ob = (ushort_t*)(g_ws + O_OFF);
  const int t = threadIdx.x, w = t >> 6, l = t & 63;
  const int l15 = l & 15, lq = l >> 4;
  const int wq_r = w >> 2, wq_c = w & 3;
  const int QM[4] = {0, 0, 1, 1}, QN[4] = {0, 1, 1, 0};
#pragma unroll
  for (int q = 0; q < 4; ++q) {
#pragma unroll
    for (int i = 0; i < 4; ++i) {
#pragma unroll
      for (int r = 0; r < 4; ++r) {
        const int m = tileM + QM[q] * 128 + wq_r * 64 + i * 16 + lq * 4 + r;
        const float lv = lsum[(size_t)bh * S_LEN + m];
        const float inv = (lv > 1e-20f) ? 1.0f / lv : 0.f;
#pragma unroll
        for (int j = 0; j < 2; ++j) {
          const int n = tileN + QN[q] * 128 + wq_c * 32 + j * 16 + l15;
          Ob[((size_t)b * S_LEN + m) * HP + h * DH + n] =
              f2bf(acc[q][i][j][r] * inv);
        }
      }
    }
  }
}

// ---------- out projection, 256² core + split-K=4, plain-store partials ----
__global__ __launch_bounds__(512, 2) void proj_kernel()
{
  __shared__ __align__(16) ushort_t SH[65536];
  ushort_t* As = SH;
  ushort_t* Bs = SH + 32768;
  const int tileM = blockIdx.y * 256, tileN = blockIdx.x * 256;
  const int ks = blockIdx.z;

  const ushort_t* A  = (const ushort_t*)(g_ws + O_OFF)
                       + (size_t)tileM * HP + ks * 1024;
  const ushort_t* Bt = (const ushort_t*)(g_ws + WPT_OFF)
                       + (size_t)tileN * HP + ks * 1024;
  floatx4 acc[4][4][2];
  gemm256_core(A, Bt, HP, HP, 1024, As, Bs, acc);

  float* part = (float*)(g_ws + PART_OFF)
                + (size_t)ks * NBAT * S_LEN * DH;
  const int t = threadIdx.x, w = t >> 6, l = t & 63;
  const int l15 = l & 15, lq = l >> 4;
  const int wq_r = w >> 2, wq_c = w & 3;
  const int QM[4] = {0, 0, 1, 1}, QN[4] = {0, 1, 1, 0};
#pragma unroll
  for (int q = 0; q < 4; ++q) {
#pragma unroll
    for (int j = 0; j < 2; ++j) {
      const int n = tileN + QN[q] * 128 + wq_c * 32 + j * 16 + l15;
#pragma unroll
      for (int i = 0; i < 4; ++i) {
#pragma unroll
        for (int r = 0; r < 4; ++r) {
          const int m = tileM + QM[q] * 128 + wq_r * 64 + i * 16 + lq * 4 + r;
          part[(size_t)m * DH + n] = acc[q][i][j][r];
        }
      }
    }
  }
}

// ---------- reduce 4 partials + bias -> fp32 out ----------
__global__ __launch_bounds__(256) void reduce_out(
    const float* __restrict__ bp, float* __restrict__ out)
{
  const float* part = (const float*)(g_ws + PART_OFF);
  const size_t N = (size_t)NBAT * S_LEN * DH;
  const size_t j = ((size_t)blockIdx.x * 256 + threadIdx.x) * 4;
  const float4 s0 = *(const float4*)(part + j);
  const float4 s1 = *(const float4*)(part + N + j);
  const float4 s2 = *(const float4*)(part + 2 * N + j);
  const float4 s3 = *(const float4*)(part + 3 * N + j);
  const float4 bv = *(const float4*)(bp + (j & (DH - 1)));
  float4 o;
  o.x = s0.x + s1.x + s2.x + s3.x + bv.x;
  o.y = s0.y + s1.y + s2.y + s3.y + bv.y;
  o.z = s0.z + s1.z + s2.z + s3.z + bv.z;
  o.w = s0.w + s1.w + s2.w + s3.w + bv.w;
  *(float4*)(out + j) = o;
}

// ---------- host ----------
extern "C" void kernel_launch(void* const* d_in, const int* in_sizes, int n_in,
                              void* d_out, int out_size, void* d_ws, size_t ws_size,
                              hipStream_t stream) {
  const float* x  = (const float*)d_in[0];
  const int*   msk= (const int*)d_in[1];
  const float* Wq = (const float*)d_in[2];
  const float* bq = (const float*)d_in[3];
  const float* Wk = (const float*)d_in[4];
  const float* bk = (const float*)d_in[5];
  const float* Wv = (const float*)d_in[6];
  const float* bv = (const float*)d_in[7];
  const float* Wp = (const float*)d_in[8];
  const float* bp = (const float*)d_in[9];
  float* out = (float*)d_out;

  // x -> bf16 (all batches)
  convert_f32_bf16<<<dim3(NBAT * S_LEN * DIN / 1024), 256, 0, stream>>>(
      x, XBF_OFF, NBAT * S_LEN * DIN);

  // weight transposes (fp32 -> bf16): Wq/Wk/Wv merged; Wp separate shape
  transpose_w3<<<dim3(16, 16, 24), 256, 0, stream>>>(Wq, Wk, Wv);
  transpose_f32_bf16<<<dim3(16, 128, 1), 256, 0, stream>>>(Wp, WPT_OFF, HP, DH);

  // zero all 32 heads' lsum; build per-batch compact key index
  zero_lsum<<<dim3(64), 256, 0, stream>>>();
  scan_mask<<<dim3(NBAT), 64, 0, stream>>>(msk);

  // Q/K/V^T for all 32 (b,h): 256² tiles -> grid (2, 8, 96)
  qkv_gemm<<<dim3(2, 8, 3 * NBH), 512, 0, stream>>>(bq, bk, bv);

  // compact K rows and V^T columns to unmasked keys (zero-padded to 256)
  compact_k<<<dim3(512, 32), 256, 0, stream>>>();
  compact_vt<<<dim3(512, 32), 256, 0, stream>>>();

  // attention in chunks of 16 heads on compacted keys
  for (int c0 = 0; c0 < NBH; c0 += 16) {
    scores_kernel<<<dim3(8, 8, 16), 512, 0, stream>>>(c0);
    pv_kernel<<<dim3(2, 8, 16), 512, 0, stream>>>(c0);
  }

  // final projection: split-K=4 plain-store partials, then reduce + bias
  proj_kernel<<<dim3(2, 32, 4), 512, 0, stream>>>();
  reduce_out<<<dim3(NBAT * S_LEN * DH / 1024), 256, 0, stream>>>(bp, out);
}